// Round 15
// baseline (99.681 us; speedup 1.0000x reference)
//
#include <hip/hip_runtime.h>

typedef __attribute__((ext_vector_type(8))) __bf16 bf16x8;
typedef __attribute__((ext_vector_type(4))) __bf16 bf16x4;
typedef __attribute__((ext_vector_type(4))) float f32x4;
typedef __attribute__((ext_vector_type(8))) _Float16 f16x8;

#define LOG2E 1.44269504088896340736f

__device__ __forceinline__ void async_load16(const void* g, void* l) {
  __builtin_amdgcn_global_load_lds(
      (const __attribute__((address_space(1))) void*)g,
      (__attribute__((address_space(3))) void*)l, 16, 0, 0);
}

__device__ __forceinline__ float fast_exp2(float x) {
#if __has_builtin(__builtin_amdgcn_exp2f)
  return __builtin_amdgcn_exp2f(x);
#else
  return __expf(x * 0.6931471805599453f);
#endif
}

// ---------------- fp32 -> bf16 convert, 3 segments in one launch ----------
__global__ void cvt3(const float* __restrict__ a, __bf16* __restrict__ oa, int na4,
                     const float* __restrict__ b, __bf16* __restrict__ ob, int nb4,
                     const float* __restrict__ c, __bf16* __restrict__ oc, int nc4) {
  int i = blockIdx.x * blockDim.x + threadIdx.x;
  int n = na4 + nb4 + nc4;
  int stride = gridDim.x * blockDim.x;
  for (; i < n; i += stride) {
    const float4* s;
    bf16x4* d;
    int j;
    if (i < na4) { s = (const float4*)a; d = (bf16x4*)oa; j = i; }
    else if (i < na4 + nb4) { s = (const float4*)b; d = (bf16x4*)ob; j = i - na4; }
    else { s = (const float4*)c; d = (bf16x4*)oc; j = i - na4 - nb4; }
    float4 v = s[j];
    bf16x4 o;
    o[0] = (__bf16)v.x; o[1] = (__bf16)v.y; o[2] = (__bf16)v.z; o[3] = (__bf16)v.w;
    d[j] = o;
  }
}

// ---------------- log2-domain bias table, per-lane fragment layout ----------
// ebT f16x8 index (((b*64+qt)*32+kt)*64 + lane); element [ni*4+r] =
//   (sigmoid(gbias[b][kt*32+16ni+ln][qt*16+4g+r]) - 0.5) * 10*alpha*log2e
__global__ __launch_bounds__(256) void build_ebias(
    const float* __restrict__ gbias, const float* __restrict__ bstr,
    _Float16* __restrict__ ebT) {
  const int gid = blockIdx.x * 256 + threadIdx.x;  // 4096 blocks
  const int lane = gid & 63;
  const int kt = (gid >> 6) & 31;
  const int qt = (gid >> 11) & 63;
  const int b = gid >> 17;
  const int g = lane >> 4, ln = lane & 15;
  const float alpha = 1.f / (1.f + __expf(-bstr[0]));
  const float bsc = 10.f * alpha * LOG2E;
  const float* base = gbias + (size_t)(b * 1024 + kt * 32 + ln) * 1024 + qt * 16 + g * 4;
  float4 va = *(const float4*)(base);                  // ni=0 row
  float4 vb = *(const float4*)(base + 16 * 1024);      // ni=1 row
  float sv[8] = {va.x, va.y, va.z, va.w, vb.x, vb.y, vb.z, vb.w};
  f16x8 o;
#pragma unroll
  for (int i = 0; i < 8; ++i)
    o[i] = (_Float16)((1.f / (1.f + __expf(-sv[i])) - 0.5f) * bsc);
  *(f16x8*)(ebT + (size_t)gid * 8) = o;
}

// ---------------- C = (A @ Bm^T + bias) [*scale] ----------------
template <int MODE>
__global__ __launch_bounds__(256) void gemm_bt(
    const __bf16* __restrict__ A, const __bf16* __restrict__ Bm,
    const float* __restrict__ bias, void* __restrict__ C0,
    __bf16* __restrict__ vT, int M, int N, int K) {
  __shared__ __align__(16) char smem[32768];
  char* lA = smem;
  char* lB = smem + 16384;
  const int t = threadIdx.x;
  const int lane = t & 63;
  const int wid = t >> 6;
  const int wm = wid >> 1, wn = wid & 1;
  const int g = lane >> 4, ln = lane & 15;
  const int m0 = blockIdx.y * 128;
  const int n0 = blockIdx.x * 128;

  const int srow = t >> 3;
  const int sswz = ((t & 7) * 16) ^ ((srow & 7) << 4);
  const size_t KB = (size_t)K * 2;
  const char* gA = (const char*)A + (size_t)m0 * KB;
  const char* gB = (const char*)Bm + (size_t)n0 * KB;

  f32x4 acc[4][4] = {};

  for (int k0 = 0; k0 < K; k0 += 64) {
    __syncthreads();
#pragma unroll
    for (int c = 0; c < 4; ++c) {
      int row = srow + 32 * c;
      async_load16(gA + (size_t)row * KB + k0 * 2 + sswz, lA + c * 4096 + t * 16);
      async_load16(gB + (size_t)row * KB + k0 * 2 + sswz, lB + c * 4096 + t * 16);
    }
    __syncthreads();
#pragma unroll
    for (int ks = 0; ks < 2; ++ks) {
      bf16x8 af[4], bf[4];
#pragma unroll
      for (int i = 0; i < 4; ++i) {
        int ar = wm * 64 + i * 16 + ln;
        int byo = (ks * 64 + g * 16) ^ ((ar & 7) << 4);
        af[i] = *(const bf16x8*)(lA + ar * 128 + byo);
        int br = wn * 64 + i * 16 + ln;
        bf[i] = *(const bf16x8*)(lB + br * 128 + byo);
      }
#pragma unroll
      for (int i = 0; i < 4; ++i)
#pragma unroll
        for (int j = 0; j < 4; ++j)
          acc[i][j] = __builtin_amdgcn_mfma_f32_16x16x32_bf16(af[i], bf[j], acc[i][j], 0, 0, 0);
    }
  }

#pragma unroll
  for (int j = 0; j < 4; ++j) {
    int col = n0 + wn * 64 + j * 16 + ln;
    float bv = bias[col];
    if (MODE == 0) {
#pragma unroll
      for (int i = 0; i < 4; ++i) {
        int row0 = m0 + wm * 64 + i * 16 + g * 4;
#pragma unroll
        for (int r = 0; r < 4; ++r)
          ((float*)C0)[(size_t)(row0 + r) * N + col] = acc[i][j][r] + bv;
      }
    } else if (col < 1024) {
      float scale = (col < 512) ? (0.125f * LOG2E) : 1.0f;
#pragma unroll
      for (int i = 0; i < 4; ++i) {
        int row0 = m0 + wm * 64 + i * 16 + g * 4;
#pragma unroll
        for (int r = 0; r < 4; ++r)
          ((__bf16*)C0)[(size_t)(row0 + r) * 1024 + col] = (__bf16)((acc[i][j][r] + bv) * scale);
      }
    } else {
      int h = (col - 1024) >> 6;
      int d = (col - 1024) & 63;
#pragma unroll
      for (int i = 0; i < 4; ++i) {
        int row0 = m0 + wm * 64 + i * 16 + g * 4;
        int b = row0 >> 10;
        bf16x4 pk;
#pragma unroll
        for (int r = 0; r < 4; ++r) pk[r] = (__bf16)(acc[i][j][r] + bv);
        *(bf16x4*)(vT + (((size_t)b * 8 + h) * 64 + d) * 1024 + (row0 & 1023)) = pk;
      }
    }
  }
}

// ---------------- fused flash attention: cooperative K/V + in-block k-split
// 1024 blocks = (b, h, qg of 4 q-tiles); 8 waves = 4 q-tiles x 2 k-halves.
// Doubles resident waves/CU vs R13 (32 vs 16): grid 1024 x 40KB LDS -> 4
// blocks/CU, 8 waves/SIMD. K/V staged cooperatively per k-half (2 gl_lds per
// wave per iter), double-buffered; counted drain vmcnt(1) keeps eb(t+2) in
// flight. No-max log2 softmax -> k-halves combine by plain summation of
// (o,l) partials through LDS at the end (R9-validated math, intra-block).
__global__ __launch_bounds__(512, 4) void attn_fused(
    const __bf16* __restrict__ qk,    // [B][N][1024]: q(log2-prescaled)|k
    const __bf16* __restrict__ vT,    // [B*8][64 d][1024 k]
    const _Float16* __restrict__ ebT, // f16 bias table
    __bf16* __restrict__ attn) {      // [B][N][512]
  __shared__ __align__(16) char smem[40960];
  const int t = threadIdx.x;
  const int lane = t & 63;
  const int wid = t >> 6;               // 0..7
  const int g = lane >> 4, ln = lane & 15;
  const int wg = ((blockIdx.x & 7) << 7) + (blockIdx.x >> 3);  // bijective, 1024%8==0
  const int b = wg >> 7;
  const int rem = wg & 127;
  const int h = rem >> 4;               // head (shared by whole block)
  const int qg = rem & 15;              // q-group of 4 tiles
  const int qx = wid & 3;               // q-tile within group
  const int kp = wid >> 2;              // k-half 0/1
  const int qt = qg * 4 + qx;
  const int q0 = qt << 4;
  const int kt0 = kp * 16;              // this half's k-tile range [kt0,kt0+16)

  char* half = smem + kp * 16384;
  char* K0 = half;            // [32 k][128B] swizzled, shared by 4 waves
  char* K1 = half + 4096;
  char* V0 = half + 8192;     // [64 d][64B] swizzled
  char* V1 = half + 12288;
  char* Ps = smem + 32768 + wid * 1024;  // per-wave P round-trip

  // Q A-frags: row = ln, k-dim = ks*32 + g*8 + j (prescaled by log2e/8)
  bf16x8 qf[2];
#pragma unroll
  for (int ks = 0; ks < 2; ++ks)
    qf[ks] = *(const bf16x8*)(qk + ((size_t)b * 1024 + q0 + ln) * 1024 +
                              h * 64 + ks * 32 + g * 8);

  float l_acc[4] = {0.f, 0.f, 0.f, 0.f};
  f32x4 o_acc[4] = {};

  const int krow = lane >> 3;
  const int ksrc = ((lane & 7) * 16) ^ (krow << 4);
  const int vrow = lane >> 2;
  const int vsrc = ((lane & 3) * 16) ^ ((vrow & 3) << 4);

  const char* qkb = (const char*)qk + (size_t)b * 1024 * 2048;
  const char* vTb = (const char*)vT + (size_t)(b * 8 + h) * 64 * 2048;
  const _Float16* ebp = ebT + (size_t)((b * 64 + qt) * 32) * 512 + lane * 8;

  // cooperative stage of global tile ktg: wave contributes K chunk qx (rows
  // [8qx,8qx+8)) and V chunk qx (d-rows [16qx,16qx+16)) of its half.
  auto stage = [&](int ktg, char* Kd, char* Vd) {
    async_load16(qkb + (size_t)(ktg * 32 + qx * 8 + krow) * 2048 + 1024 + h * 128 + ksrc,
                 Kd + qx * 1024 + lane * 16);
    async_load16(vTb + (size_t)(qx * 16 + vrow) * 2048 + (size_t)(ktg * 32) * 2 + vsrc,
                 Vd + qx * 1024 + lane * 16);
  };

  // prologue: tile kt0 into buf0; eb(kt0),eb(kt0+1) to regs; drain; barrier
  stage(kt0, K0, V0);
  f16x8 ebc = *(const f16x8*)(ebp + (size_t)kt0 * 512);
  f16x8 ebn = *(const f16x8*)(ebp + (size_t)(kt0 + 1) * 512);
  asm volatile("s_waitcnt vmcnt(0)" ::: "memory");
  __syncthreads();

  for (int kt = 0; kt < 16; ++kt) {
    char* Kp = (kt & 1) ? K1 : K0;
    char* Vp = (kt & 1) ? V1 : V0;
    char* Kn = (kt & 1) ? K0 : K1;
    char* Vn = (kt & 1) ? V0 : V1;
    const int ktn = kt0 + ((kt + 1) & 15);  // next tile (wrap in own half)
    const int kt2 = kt0 + ((kt + 2) & 15);  // eb 2-ahead (wrap in own half)

    // [1] issue next-tile staging (2 gl_lds per wave), fenced
    stage(ktn, Kn, Vn);
    __builtin_amdgcn_sched_barrier(0);
    // [2] eb(t+2) register prefetch -- the op vmcnt(1) leaves in flight
    f16x8 ebn2 = *(const f16x8*)(ebp + (size_t)kt2 * 512);
    __builtin_amdgcn_sched_barrier(0);

    // [3] frag reads of tile t from this half's shared buffers
    bf16x8 kf[2][2];
#pragma unroll
    for (int ni = 0; ni < 2; ++ni) {
      int br = ni * 16 + ln;
      int sw = (br & 7) << 4;
#pragma unroll
      for (int ks = 0; ks < 2; ++ks)
        kf[ni][ks] = *(const bf16x8*)(Kp + br * 128 + ((ks * 64 + g * 16) ^ sw));
    }
    bf16x8 vf[4];
#pragma unroll
    for (int di = 0; di < 4; ++di)
      vf[di] = *(const bf16x8*)(Vp + (di * 16 + ln) * 64 + ((g * 16) ^ ((ln & 3) << 4)));

    // S = QK^T + bias via C-operand (D: q = 4g + r, key = ni*16 + ln)
    f32x4 lbf0 = {(float)ebc[0], (float)ebc[1], (float)ebc[2], (float)ebc[3]};
    f32x4 lbf1 = {(float)ebc[4], (float)ebc[5], (float)ebc[6], (float)ebc[7]};
    f32x4 s[2];
    s[0] = __builtin_amdgcn_mfma_f32_16x16x32_bf16(qf[0], kf[0][0], lbf0, 0, 0, 0);
    s[0] = __builtin_amdgcn_mfma_f32_16x16x32_bf16(qf[1], kf[0][1], s[0], 0, 0, 0);
    s[1] = __builtin_amdgcn_mfma_f32_16x16x32_bf16(qf[0], kf[1][0], lbf1, 0, 0, 0);
    s[1] = __builtin_amdgcn_mfma_f32_16x16x32_bf16(qf[1], kf[1][1], s[1], 0, 0, 0);

    // p = 2^s; accumulate l; P round-trip through wave-private LDS
#pragma unroll
    for (int r = 0; r < 4; ++r) {
      float p0 = fast_exp2(s[0][r]);
      float p1 = fast_exp2(s[1][r]);
      s[0][r] = p0; s[1][r] = p1;
      l_acc[r] += p0 + p1;
    }
#pragma unroll
    for (int ni = 0; ni < 2; ++ni)
#pragma unroll
      for (int r = 0; r < 4; ++r) {
        int q = g * 4 + r;
        *(__bf16*)(Ps + q * 64 + ((ni * 32 + ln * 2) ^ (((q >> 1) & 3) << 4))) =
            (__bf16)s[ni][r];
      }
    bf16x8 pf = *(const bf16x8*)(Ps + ln * 64 + ((g * 16) ^ (((ln >> 1) & 3) << 4)));

    // O += P V
#pragma unroll
    for (int di = 0; di < 4; ++di)
      o_acc[di] = __builtin_amdgcn_mfma_f32_16x16x32_bf16(pf, vf[di], o_acc[di], 0, 0, 0);

    // [4] counted drain: outstanding [eb(t+1), K(t+1), V(t+1), eb(t+2)];
    //     vmcnt(1) retires all but eb(t+2). Barrier publishes buf(t+1).
    asm volatile("s_waitcnt vmcnt(1)" ::: "memory");
    __builtin_amdgcn_sched_barrier(0);
    __syncthreads();
    ebc = ebn;
    ebn = ebn2;
  }

  // ---- k-half combine: no-max softmax => plain summation of partials ----
  if (kp == 1) {
    char* dst = smem + 16384 + qx * 4096;  // half1 staging region, now dead
#pragma unroll
    for (int di = 0; di < 4; ++di)
      *(f32x4*)(dst + di * 1024 + lane * 16) = o_acc[di];
    f32x4 lv = {l_acc[0], l_acc[1], l_acc[2], l_acc[3]};
    *(f32x4*)(Ps + lane * 16) = lv;
  }
  __syncthreads();
  if (kp == 0) {
    const char* src = smem + 16384 + qx * 4096;
#pragma unroll
    for (int di = 0; di < 4; ++di) {
      f32x4 ov = *(const f32x4*)(src + di * 1024 + lane * 16);
#pragma unroll
      for (int r = 0; r < 4; ++r) o_acc[di][r] += ov[r];
    }
    f32x4 lv = *(const f32x4*)(smem + 32768 + (wid + 4) * 1024 + lane * 16);
#pragma unroll
    for (int r = 0; r < 4; ++r) l_acc[r] += lv[r];

    // reduce l over the 16 ln-lanes, normalize, store
#pragma unroll
    for (int r = 0; r < 4; ++r) {
      float rs = l_acc[r];
#pragma unroll
      for (int off = 1; off < 16; off <<= 1)
        rs += __shfl_xor(rs, off, 64);
      float inv = 1.f / rs;
      int q = q0 + g * 4 + r;
#pragma unroll
      for (int di = 0; di < 4; ++di)
        attn[((size_t)b * 1024 + q) * 512 + h * 64 + di * 16 + ln] =
            (__bf16)(o_acc[di][r] * inv);
    }
  }
}

extern "C" void kernel_launch(void* const* d_in, const int* in_sizes, int n_in,
                              void* d_out, int out_size, void* d_ws, size_t ws_size,
                              hipStream_t stream) {
  const float* x     = (const float*)d_in[0];
  const float* gb    = (const float*)d_in[1];
  const float* w_in  = (const float*)d_in[2];
  const float* b_in  = (const float*)d_in[3];
  const float* w_out = (const float*)d_in[4];
  const float* b_out = (const float*)d_in[5];
  const float* bstr  = (const float*)d_in[6];

  char* ws = (char*)d_ws;
  __bf16* qk    = (__bf16*)(ws);                      // 16,777,216 B
  __bf16* vT    = (__bf16*)(ws + 16777216);           //  8,388,608 B
  __bf16* xb    = (__bf16*)(ws + 25165824);           //  8,388,608 B
  __bf16* w1    = (__bf16*)(ws + 33554432);           //  1,572,864 B
  __bf16* w2    = (__bf16*)(ws + 35127296);           //    524,288 B
  _Float16* ebT = (_Float16*)(ws + 35651584);         // 16,777,216 B
  __bf16* attn_buf = xb;  // alias: x_bf16 dead after GEMM1

  cvt3<<<2560, 256, 0, stream>>>(x, xb, (8 * 1024 * 512) / 4,
                                 w_in, w1, (1536 * 512) / 4,
                                 w_out, w2, (512 * 512) / 4);
  build_ebias<<<4096, 256, 0, stream>>>(gb, bstr, ebT);

  gemm_bt<1><<<dim3(12, 64), 256, 0, stream>>>(xb, w1, b_in, qk, vT, 8192, 1536, 512);
  attn_fused<<<1024, 512, 0, stream>>>(qk, vT, ebT, attn_buf);
  gemm_bt<0><<<dim3(4, 64), 256, 0, stream>>>(attn_buf, w2, b_out, d_out, nullptr, 8192, 512, 512);
}

// Round 16
// 90.319 us; speedup vs baseline: 1.1036x; 1.1036x over previous
//
#include <hip/hip_runtime.h>

typedef __attribute__((ext_vector_type(8))) __bf16 bf16x8;
typedef __attribute__((ext_vector_type(4))) __bf16 bf16x4;
typedef __attribute__((ext_vector_type(4))) float f32x4;
typedef __attribute__((ext_vector_type(8))) _Float16 f16x8;

#define LOG2E 1.44269504088896340736f

__device__ __forceinline__ void async_load16(const void* g, void* l) {
  __builtin_amdgcn_global_load_lds(
      (const __attribute__((address_space(1))) void*)g,
      (__attribute__((address_space(3))) void*)l, 16, 0, 0);
}

__device__ __forceinline__ float fast_exp2(float x) {
#if __has_builtin(__builtin_amdgcn_exp2f)
  return __builtin_amdgcn_exp2f(x);
#else
  return __expf(x * 0.6931471805599453f);
#endif
}

// ---------------- prep: build_ebias (blocks 0..4095) + cvt3 (4096..6655) ---
// ebT f16x8 index (((b*64+qt)*32+kt)*64 + lane); element [ni*4+r] =
//   (sigmoid(gbias[b][kt*32+16ni+ln][qt*16+4g+r]) - 0.5) * 10*alpha*log2e
__global__ __launch_bounds__(256) void prep(
    const float* __restrict__ gbias, const float* __restrict__ bstr,
    _Float16* __restrict__ ebT,
    const float* __restrict__ a, __bf16* __restrict__ oa, int na4,
    const float* __restrict__ b2, __bf16* __restrict__ ob, int nb4,
    const float* __restrict__ c, __bf16* __restrict__ oc, int nc4) {
  if (blockIdx.x < 4096) {
    const int gid = blockIdx.x * 256 + threadIdx.x;
    const int lane = gid & 63;
    const int kt = (gid >> 6) & 31;
    const int qt = (gid >> 11) & 63;
    const int b = gid >> 17;
    const int g = lane >> 4, ln = lane & 15;
    const float alpha = 1.f / (1.f + __expf(-bstr[0]));
    const float bsc = 10.f * alpha * LOG2E;
    const float* base = gbias + (size_t)(b * 1024 + kt * 32 + ln) * 1024 + qt * 16 + g * 4;
    float4 va = *(const float4*)(base);              // ni=0 row
    float4 vb = *(const float4*)(base + 16 * 1024);  // ni=1 row
    float sv[8] = {va.x, va.y, va.z, va.w, vb.x, vb.y, vb.z, vb.w};
    f16x8 o;
#pragma unroll
    for (int i = 0; i < 8; ++i)
      o[i] = (_Float16)((1.f / (1.f + __expf(-sv[i])) - 0.5f) * bsc);
    *(f16x8*)(ebT + (size_t)gid * 8) = o;
  } else {
    int i = (blockIdx.x - 4096) * 256 + threadIdx.x;
    int n = na4 + nb4 + nc4;
    int stride = 2560 * 256;
    for (; i < n; i += stride) {
      const float4* s;
      bf16x4* d;
      int j;
      if (i < na4) { s = (const float4*)a; d = (bf16x4*)oa; j = i; }
      else if (i < na4 + nb4) { s = (const float4*)b2; d = (bf16x4*)ob; j = i - na4; }
      else { s = (const float4*)c; d = (bf16x4*)oc; j = i - na4 - nb4; }
      float4 v = s[j];
      bf16x4 o;
      o[0] = (__bf16)v.x; o[1] = (__bf16)v.y; o[2] = (__bf16)v.z; o[3] = (__bf16)v.w;
      d[j] = o;
    }
  }
}

// ---------------- C = (A @ Bm^T + bias) [*scale] ----------------
template <int MODE>
__global__ __launch_bounds__(256) void gemm_bt(
    const __bf16* __restrict__ A, const __bf16* __restrict__ Bm,
    const float* __restrict__ bias, void* __restrict__ C0,
    __bf16* __restrict__ vT, int M, int N, int K) {
  __shared__ __align__(16) char smem[32768];
  char* lA = smem;
  char* lB = smem + 16384;
  const int t = threadIdx.x;
  const int lane = t & 63;
  const int wid = t >> 6;
  const int wm = wid >> 1, wn = wid & 1;
  const int g = lane >> 4, ln = lane & 15;
  const int m0 = blockIdx.y * 128;
  const int n0 = blockIdx.x * 128;

  const int srow = t >> 3;
  const int sswz = ((t & 7) * 16) ^ ((srow & 7) << 4);
  const size_t KB = (size_t)K * 2;
  const char* gA = (const char*)A + (size_t)m0 * KB;
  const char* gB = (const char*)Bm + (size_t)n0 * KB;

  f32x4 acc[4][4] = {};

  for (int k0 = 0; k0 < K; k0 += 64) {
    __syncthreads();
#pragma unroll
    for (int c = 0; c < 4; ++c) {
      int row = srow + 32 * c;
      async_load16(gA + (size_t)row * KB + k0 * 2 + sswz, lA + c * 4096 + t * 16);
      async_load16(gB + (size_t)row * KB + k0 * 2 + sswz, lB + c * 4096 + t * 16);
    }
    __syncthreads();
#pragma unroll
    for (int ks = 0; ks < 2; ++ks) {
      bf16x8 af[4], bf[4];
#pragma unroll
      for (int i = 0; i < 4; ++i) {
        int ar = wm * 64 + i * 16 + ln;
        int byo = (ks * 64 + g * 16) ^ ((ar & 7) << 4);
        af[i] = *(const bf16x8*)(lA + ar * 128 + byo);
        int br = wn * 64 + i * 16 + ln;
        bf[i] = *(const bf16x8*)(lB + br * 128 + byo);
      }
#pragma unroll
      for (int i = 0; i < 4; ++i)
#pragma unroll
        for (int j = 0; j < 4; ++j)
          acc[i][j] = __builtin_amdgcn_mfma_f32_16x16x32_bf16(af[i], bf[j], acc[i][j], 0, 0, 0);
    }
  }

#pragma unroll
  for (int j = 0; j < 4; ++j) {
    int col = n0 + wn * 64 + j * 16 + ln;
    float bv = bias[col];
    if (MODE == 0) {
#pragma unroll
      for (int i = 0; i < 4; ++i) {
        int row0 = m0 + wm * 64 + i * 16 + g * 4;
#pragma unroll
        for (int r = 0; r < 4; ++r)
          ((float*)C0)[(size_t)(row0 + r) * N + col] = acc[i][j][r] + bv;
      }
    } else if (col < 1024) {
      float scale = (col < 512) ? (0.125f * LOG2E) : 1.0f;
#pragma unroll
      for (int i = 0; i < 4; ++i) {
        int row0 = m0 + wm * 64 + i * 16 + g * 4;
#pragma unroll
        for (int r = 0; r < 4; ++r)
          ((__bf16*)C0)[(size_t)(row0 + r) * 1024 + col] = (__bf16)((acc[i][j][r] + bv) * scale);
      }
    } else {
      int h = (col - 1024) >> 6;
      int d = (col - 1024) & 63;
#pragma unroll
      for (int i = 0; i < 4; ++i) {
        int row0 = m0 + wm * 64 + i * 16 + g * 4;
        int b = row0 >> 10;
        bf16x4 pk;
#pragma unroll
        for (int r = 0; r < 4; ++r) pk[r] = (__bf16)(acc[i][j][r] + bv);
        *(bf16x4*)(vT + (((size_t)b * 8 + h) * 64 + d) * 1024 + (row0 & 1023)) = pk;
      }
    }
  }
}

// ---------------- fused flash attention: cooperative K/V, 2 tiles/period --
// R13 structure (512 blocks = (b,h,qg), 8 waves, cooperative staging) with
// TWO k-tiles per barrier period (16 periods): halves barrier/drain overhead
// per unit work and doubles within-period ILP (sub-tile B's frag reads
// overlap sub-tile A's compute). Each sub-tile keeps the R13-validated
// [32k][128B] K / [64d][64B] V layouts. Buffer sets double-buffered; sub-
// tiles share the per-wave P slot (per-wave DS ordering makes the A-read ->
// B-write sequence safe, same argument as cross-iteration P reuse).
__global__ __launch_bounds__(512, 4) void attn_fused(
    const __bf16* __restrict__ qk,    // [B][N][1024]: q(log2-prescaled)|k
    const __bf16* __restrict__ vT,    // [B*8][64 d][1024 k]
    const _Float16* __restrict__ ebT, // f16 bias table
    __bf16* __restrict__ attn) {      // [B][N][512]
  __shared__ __align__(16) char smem[40960];
  const int t = threadIdx.x;
  const int lane = t & 63;
  const int wid = t >> 6;               // 0..7 = q-tile within group
  const int g = lane >> 4, ln = lane & 15;
  const int wg = ((blockIdx.x & 7) << 6) + (blockIdx.x >> 3);  // XCD: b = wg>>6
  const int b = wg >> 6;
  const int rem = wg & 63;
  const int h = rem >> 3;               // head (shared by whole block)
  const int qg = rem & 7;
  const int qt = qg * 8 + wid;          // this wave's q-tile
  const int q0 = qt << 4;

  // buffer set s at smem + s*16384: [KA 4K][KB 4K][VA 4K][VB 4K]
  char* Ps = smem + 32768 + wid * 1024;  // per-wave P round-trip

  // Q A-frags: row = ln, k-dim = ks*32 + g*8 + j (prescaled by log2e/8)
  bf16x8 qf[2];
#pragma unroll
  for (int ks = 0; ks < 2; ++ks)
    qf[ks] = *(const bf16x8*)(qk + ((size_t)b * 1024 + q0 + ln) * 1024 +
                              h * 64 + ks * 32 + g * 8);

  float l_acc[4] = {0.f, 0.f, 0.f, 0.f};
  f32x4 o_acc[4] = {};

  const int krow = lane >> 3;
  const int ksrc = ((lane & 7) * 16) ^ (krow << 4);
  const int vrow = lane >> 2;
  const int vsrc = ((lane & 3) * 16) ^ ((vrow & 3) << 4);

  const char* qkb = (const char*)qk + (size_t)b * 1024 * 2048;
  const char* vTb = (const char*)vT + (size_t)(b * 8 + h) * 64 * 2048;
  const _Float16* ebp = ebT + (size_t)((b * 64 + qt) * 32) * 512 + lane * 8;

  // cooperative stage of period p (k-tiles 2p, 2p+1) into buffer set `set`:
  // waves 0-3 stage both K sub-tiles' rows [8w,8w+8); waves 4-7 both V
  // sub-tiles' d-rows [16(w-4),16(w-4)+16). 2 gl_lds per wave.
  auto stage = [&](int p, char* set) {
    if (wid < 4) {
      async_load16(qkb + (size_t)((2 * p) * 32 + wid * 8 + krow) * 2048 + 1024 + h * 128 + ksrc,
                   set + wid * 1024 + lane * 16);
      async_load16(qkb + (size_t)((2 * p + 1) * 32 + wid * 8 + krow) * 2048 + 1024 + h * 128 + ksrc,
                   set + 4096 + wid * 1024 + lane * 16);
    } else {
      int cc = wid - 4;
      async_load16(vTb + (size_t)(cc * 16 + vrow) * 2048 + (size_t)(2 * p) * 64 + vsrc,
                   set + 8192 + cc * 1024 + lane * 16);
      async_load16(vTb + (size_t)(cc * 16 + vrow) * 2048 + (size_t)(2 * p + 1) * 64 + vsrc,
                   set + 12288 + cc * 1024 + lane * 16);
    }
  };

  // one sub-tile's full pipeline (R13-validated body)
  auto process = [&](const char* Kp, const char* Vp, f16x8 ebv) {
    bf16x8 kf[2][2];
#pragma unroll
    for (int ni = 0; ni < 2; ++ni) {
      int br = ni * 16 + ln;
      int sw = (br & 7) << 4;
#pragma unroll
      for (int ks = 0; ks < 2; ++ks)
        kf[ni][ks] = *(const bf16x8*)(Kp + br * 128 + ((ks * 64 + g * 16) ^ sw));
    }
    bf16x8 vf[4];
#pragma unroll
    for (int di = 0; di < 4; ++di)
      vf[di] = *(const bf16x8*)(Vp + (di * 16 + ln) * 64 + ((g * 16) ^ ((ln & 3) << 4)));

    f32x4 lbf0 = {(float)ebv[0], (float)ebv[1], (float)ebv[2], (float)ebv[3]};
    f32x4 lbf1 = {(float)ebv[4], (float)ebv[5], (float)ebv[6], (float)ebv[7]};
    f32x4 s[2];
    s[0] = __builtin_amdgcn_mfma_f32_16x16x32_bf16(qf[0], kf[0][0], lbf0, 0, 0, 0);
    s[0] = __builtin_amdgcn_mfma_f32_16x16x32_bf16(qf[1], kf[0][1], s[0], 0, 0, 0);
    s[1] = __builtin_amdgcn_mfma_f32_16x16x32_bf16(qf[0], kf[1][0], lbf1, 0, 0, 0);
    s[1] = __builtin_amdgcn_mfma_f32_16x16x32_bf16(qf[1], kf[1][1], s[1], 0, 0, 0);

#pragma unroll
    for (int r = 0; r < 4; ++r) {
      float p0 = fast_exp2(s[0][r]);
      float p1 = fast_exp2(s[1][r]);
      s[0][r] = p0; s[1][r] = p1;
      l_acc[r] += p0 + p1;
    }
#pragma unroll
    for (int ni = 0; ni < 2; ++ni)
#pragma unroll
      for (int r = 0; r < 4; ++r) {
        int q = g * 4 + r;
        *(__bf16*)(Ps + q * 64 + ((ni * 32 + ln * 2) ^ (((q >> 1) & 3) << 4))) =
            (__bf16)s[ni][r];
      }
    bf16x8 pf = *(const bf16x8*)(Ps + ln * 64 + ((g * 16) ^ (((ln >> 1) & 3) << 4)));

#pragma unroll
    for (int di = 0; di < 4; ++di)
      o_acc[di] = __builtin_amdgcn_mfma_f32_16x16x32_bf16(pf, vf[di], o_acc[di], 0, 0, 0);
  };

  // prologue: period 0 into set 0; eb pair for period 0; drain; barrier
  stage(0, smem);
  f16x8 eba = *(const f16x8*)(ebp);
  f16x8 ebb = *(const f16x8*)(ebp + 512);
  asm volatile("s_waitcnt vmcnt(0)" ::: "memory");
  __syncthreads();

  for (int p = 0; p < 16; ++p) {
    char* cur = smem + (p & 1) * 16384;
    char* nxt = smem + ((p + 1) & 1) * 16384;
    const int pn = (p + 1) & 15;  // wrapped prefetch period

    // [1] issue next-period staging (2 gl_lds) + eb pair for period p+1
    stage(pn, nxt);
    f16x8 eba2 = *(const f16x8*)(ebp + (size_t)(2 * pn) * 512);
    f16x8 ebb2 = *(const f16x8*)(ebp + (size_t)(2 * pn + 1) * 512);
    __builtin_amdgcn_sched_barrier(0);

    // [2] sub-tile A then B (B's frag reads overlap A's compute)
    process(cur, cur + 8192, eba);
    process(cur + 4096, cur + 12288, ebb);

    // [3] drain own VMEM (issued a full double-period of compute ago)
    asm volatile("s_waitcnt vmcnt(0)" ::: "memory");
    __builtin_amdgcn_sched_barrier(0);
    __syncthreads();
    eba = eba2;
    ebb = ebb2;
  }

  // reduce l over the 16 ln-lanes, normalize, store
#pragma unroll
  for (int r = 0; r < 4; ++r) {
    float rs = l_acc[r];
#pragma unroll
    for (int off = 1; off < 16; off <<= 1)
      rs += __shfl_xor(rs, off, 64);
    float inv = 1.f / rs;
    int q = q0 + g * 4 + r;
#pragma unroll
    for (int di = 0; di < 4; ++di)
      attn[((size_t)b * 1024 + q) * 512 + h * 64 + di * 16 + ln] =
          (__bf16)(o_acc[di][r] * inv);
  }
}

extern "C" void kernel_launch(void* const* d_in, const int* in_sizes, int n_in,
                              void* d_out, int out_size, void* d_ws, size_t ws_size,
                              hipStream_t stream) {
  const float* x     = (const float*)d_in[0];
  const float* gb    = (const float*)d_in[1];
  const float* w_in  = (const float*)d_in[2];
  const float* b_in  = (const float*)d_in[3];
  const float* w_out = (const float*)d_in[4];
  const float* b_out = (const float*)d_in[5];
  const float* bstr  = (const float*)d_in[6];

  char* ws = (char*)d_ws;
  __bf16* qk    = (__bf16*)(ws);                      // 16,777,216 B
  __bf16* vT    = (__bf16*)(ws + 16777216);           //  8,388,608 B
  __bf16* xb    = (__bf16*)(ws + 25165824);           //  8,388,608 B
  __bf16* w1    = (__bf16*)(ws + 33554432);           //  1,572,864 B
  __bf16* w2    = (__bf16*)(ws + 35127296);           //    524,288 B
  _Float16* ebT = (_Float16*)(ws + 35651584);         // 16,777,216 B
  __bf16* attn_buf = xb;  // alias: x_bf16 dead after GEMM1

  prep<<<6656, 256, 0, stream>>>(gb, bstr, ebT,
                                 x, xb, (8 * 1024 * 512) / 4,
                                 w_in, w1, (1536 * 512) / 4,
                                 w_out, w2, (512 * 512) / 4);

  gemm_bt<1><<<dim3(12, 64), 256, 0, stream>>>(xb, w1, b_in, qk, vT, 8192, 1536, 512);
  attn_fused<<<512, 512, 0, stream>>>(qk, vT, ebT, attn_buf);
  gemm_bt<0><<<dim3(4, 64), 256, 0, stream>>>(attn_buf, w2, b_out, d_out, nullptr, 8192, 512, 512);
}

// Round 17
// 89.749 us; speedup vs baseline: 1.1107x; 1.0064x over previous
//
#include <hip/hip_runtime.h>

typedef __attribute__((ext_vector_type(8))) __bf16 bf16x8;
typedef __attribute__((ext_vector_type(4))) __bf16 bf16x4;
typedef __attribute__((ext_vector_type(4))) float f32x4;
typedef __attribute__((ext_vector_type(8))) _Float16 f16x8;

#define LOG2E 1.44269504088896340736f

__device__ __forceinline__ void async_load16(const void* g, void* l) {
  __builtin_amdgcn_global_load_lds(
      (const __attribute__((address_space(1))) void*)g,
      (__attribute__((address_space(3))) void*)l, 16, 0, 0);
}

__device__ __forceinline__ float fast_exp2(float x) {
#if __has_builtin(__builtin_amdgcn_exp2f)
  return __builtin_amdgcn_exp2f(x);
#else
  return __expf(x * 0.6931471805599453f);
#endif
}

// ---------------- prep: build_ebias (blocks 0..4095) + cvt3 (4096..6655) ---
__global__ __launch_bounds__(256) void prep(
    const float* __restrict__ gbias, const float* __restrict__ bstr,
    _Float16* __restrict__ ebT,
    const float* __restrict__ a, __bf16* __restrict__ oa, int na4,
    const float* __restrict__ b2, __bf16* __restrict__ ob, int nb4,
    const float* __restrict__ c, __bf16* __restrict__ oc, int nc4) {
  if (blockIdx.x < 4096) {
    const int gid = blockIdx.x * 256 + threadIdx.x;
    const int lane = gid & 63;
    const int kt = (gid >> 6) & 31;
    const int qt = (gid >> 11) & 63;
    const int b = gid >> 17;
    const int g = lane >> 4, ln = lane & 15;
    const float alpha = 1.f / (1.f + __expf(-bstr[0]));
    const float bsc = 10.f * alpha * LOG2E;
    const float* base = gbias + (size_t)(b * 1024 + kt * 32 + ln) * 1024 + qt * 16 + g * 4;
    float4 va = *(const float4*)(base);              // ni=0 row
    float4 vb = *(const float4*)(base + 16 * 1024);  // ni=1 row
    float sv[8] = {va.x, va.y, va.z, va.w, vb.x, vb.y, vb.z, vb.w};
    f16x8 o;
#pragma unroll
    for (int i = 0; i < 8; ++i)
      o[i] = (_Float16)((1.f / (1.f + __expf(-sv[i])) - 0.5f) * bsc);
    *(f16x8*)(ebT + (size_t)gid * 8) = o;
  } else {
    int i = (blockIdx.x - 4096) * 256 + threadIdx.x;
    int n = na4 + nb4 + nc4;
    int stride = 2560 * 256;
    for (; i < n; i += stride) {
      const float4* s;
      bf16x4* d;
      int j;
      if (i < na4) { s = (const float4*)a; d = (bf16x4*)oa; j = i; }
      else if (i < na4 + nb4) { s = (const float4*)b2; d = (bf16x4*)ob; j = i - na4; }
      else { s = (const float4*)c; d = (bf16x4*)oc; j = i - na4 - nb4; }
      float4 v = s[j];
      bf16x4 o;
      o[0] = (__bf16)v.x; o[1] = (__bf16)v.y; o[2] = (__bf16)v.z; o[3] = (__bf16)v.w;
      d[j] = o;
    }
  }
}

// ---------------- C = (A @ Bm^T + bias) [*scale] ----------------
// 1D grid with bijective XCD chunking: blocks sharing an A m-panel land on
// one XCD (B panels cache fully in each XCD L2). nt = N/128 tiles.
template <int MODE>
__global__ __launch_bounds__(256) void gemm_bt(
    const __bf16* __restrict__ A, const __bf16* __restrict__ Bm,
    const float* __restrict__ bias, void* __restrict__ C0,
    __bf16* __restrict__ vT, int M, int N, int K, int nt) {
  __shared__ __align__(16) char smem[32768];
  char* lA = smem;
  char* lB = smem + 16384;
  const int t = threadIdx.x;
  const int lane = t & 63;
  const int wid = t >> 6;
  const int wm = wid >> 1, wn = wid & 1;
  const int g = lane >> 4, ln = lane & 15;
  const int qchunk = gridDim.x >> 3;  // gridDim.x % 8 == 0
  const int wg = (blockIdx.x & 7) * qchunk + (blockIdx.x >> 3);
  const int m0 = (wg / nt) * 128;
  const int n0 = (wg % nt) * 128;

  const int srow = t >> 3;
  const int sswz = ((t & 7) * 16) ^ ((srow & 7) << 4);
  const size_t KB = (size_t)K * 2;
  const char* gA = (const char*)A + (size_t)m0 * KB;
  const char* gB = (const char*)Bm + (size_t)n0 * KB;

  f32x4 acc[4][4] = {};

  for (int k0 = 0; k0 < K; k0 += 64) {
    __syncthreads();
#pragma unroll
    for (int c = 0; c < 4; ++c) {
      int row = srow + 32 * c;
      async_load16(gA + (size_t)row * KB + k0 * 2 + sswz, lA + c * 4096 + t * 16);
      async_load16(gB + (size_t)row * KB + k0 * 2 + sswz, lB + c * 4096 + t * 16);
    }
    __syncthreads();
#pragma unroll
    for (int ks = 0; ks < 2; ++ks) {
      bf16x8 af[4], bf[4];
#pragma unroll
      for (int i = 0; i < 4; ++i) {
        int ar = wm * 64 + i * 16 + ln;
        int byo = (ks * 64 + g * 16) ^ ((ar & 7) << 4);
        af[i] = *(const bf16x8*)(lA + ar * 128 + byo);
        int br = wn * 64 + i * 16 + ln;
        bf[i] = *(const bf16x8*)(lB + br * 128 + byo);
      }
#pragma unroll
      for (int i = 0; i < 4; ++i)
#pragma unroll
        for (int j = 0; j < 4; ++j)
          acc[i][j] = __builtin_amdgcn_mfma_f32_16x16x32_bf16(af[i], bf[j], acc[i][j], 0, 0, 0);
    }
  }

#pragma unroll
  for (int j = 0; j < 4; ++j) {
    int col = n0 + wn * 64 + j * 16 + ln;
    float bv = bias[col];
    if (MODE == 0) {
#pragma unroll
      for (int i = 0; i < 4; ++i) {
        int row0 = m0 + wm * 64 + i * 16 + g * 4;
#pragma unroll
        for (int r = 0; r < 4; ++r)
          ((float*)C0)[(size_t)(row0 + r) * N + col] = acc[i][j][r] + bv;
      }
    } else if (col < 1024) {
      float scale = (col < 512) ? (0.125f * LOG2E) : 1.0f;
#pragma unroll
      for (int i = 0; i < 4; ++i) {
        int row0 = m0 + wm * 64 + i * 16 + g * 4;
#pragma unroll
        for (int r = 0; r < 4; ++r)
          ((__bf16*)C0)[(size_t)(row0 + r) * 1024 + col] = (__bf16)((acc[i][j][r] + bv) * scale);
      }
    } else {
      int h = (col - 1024) >> 6;
      int d = (col - 1024) & 63;
#pragma unroll
      for (int i = 0; i < 4; ++i) {
        int row0 = m0 + wm * 64 + i * 16 + g * 4;
        int b = row0 >> 10;
        bf16x4 pk;
#pragma unroll
        for (int r = 0; r < 4; ++r) pk[r] = (__bf16)(acc[i][j][r] + bv);
        *(bf16x4*)(vT + (((size_t)b * 8 + h) * 64 + d) * 1024 + (row0 & 1023)) = pk;
      }
    }
  }
}

// ---------------- fused flash attention: cooperative K/V, 4 tiles/period --
// 512 blocks = (b,h,qg), 8 waves. FOUR k-tiles per barrier period (8
// periods): grid is 2 blocks/CU regardless, so LDS 72KB is free -- barriers
// and drains amortize 4x vs R13. Sub-tile layouts unchanged (R13-validated).
__global__ __launch_bounds__(512, 4) void attn_fused(
    const __bf16* __restrict__ qk,    // [B][N][1024]: q(log2-prescaled)|k
    const __bf16* __restrict__ vT,    // [B*8][64 d][1024 k]
    const _Float16* __restrict__ ebT, // f16 bias table
    __bf16* __restrict__ attn) {      // [B][N][512]
  __shared__ __align__(16) char smem[73728];
  const int t = threadIdx.x;
  const int lane = t & 63;
  const int wid = t >> 6;               // 0..7 = q-tile within group
  const int g = lane >> 4, ln = lane & 15;
  const int wg = ((blockIdx.x & 7) << 6) + (blockIdx.x >> 3);  // XCD: b = wg>>6
  const int b = wg >> 6;
  const int rem = wg & 63;
  const int h = rem >> 3;               // head (shared by whole block)
  const int qg = rem & 7;
  const int qt = qg * 8 + wid;          // this wave's q-tile
  const int q0 = qt << 4;

  // buffer set s at smem + s*32768: [K0..K3 4K each][V0..V3 4K each]
  char* Ps = smem + 65536 + wid * 1024;  // per-wave P round-trip

  // Q A-frags: row = ln, k-dim = ks*32 + g*8 + j (prescaled by log2e/8)
  bf16x8 qf[2];
#pragma unroll
  for (int ks = 0; ks < 2; ++ks)
    qf[ks] = *(const bf16x8*)(qk + ((size_t)b * 1024 + q0 + ln) * 1024 +
                              h * 64 + ks * 32 + g * 8);

  float l_acc[4] = {0.f, 0.f, 0.f, 0.f};
  f32x4 o_acc[4] = {};

  const int krow = lane >> 3;
  const int ksrc = ((lane & 7) * 16) ^ (krow << 4);
  const int vrow = lane >> 2;
  const int vsrc = ((lane & 3) * 16) ^ ((vrow & 3) << 4);

  const char* qkb = (const char*)qk + (size_t)b * 1024 * 2048;
  const char* vTb = (const char*)vT + (size_t)(b * 8 + h) * 64 * 2048;
  const _Float16* ebp = ebT + (size_t)((b * 64 + qt) * 32) * 512 + lane * 8;

  // cooperative stage of period p (k-tiles 4p..4p+3) into buffer set `set`:
  // waves 0-3 stage the 4 K sub-tiles' rows [8w,8w+8); waves 4-7 the 4 V
  // sub-tiles' d-rows [16(w-4),16(w-4)+16). 4 gl_lds per wave.
  auto stage = [&](int p, char* set) {
    if (wid < 4) {
#pragma unroll
      for (int j = 0; j < 4; ++j)
        async_load16(qkb + (size_t)((4 * p + j) * 32 + wid * 8 + krow) * 2048 +
                         1024 + h * 128 + ksrc,
                     set + j * 4096 + wid * 1024 + lane * 16);
    } else {
      int cc = wid - 4;
#pragma unroll
      for (int j = 0; j < 4; ++j)
        async_load16(vTb + (size_t)(cc * 16 + vrow) * 2048 + (size_t)(4 * p + j) * 64 + vsrc,
                     set + 16384 + j * 4096 + cc * 1024 + lane * 16);
    }
  };

  // one sub-tile's full pipeline (R13-validated body)
  auto process = [&](const char* Kp, const char* Vp, f16x8 ebv) {
    bf16x8 kf[2][2];
#pragma unroll
    for (int ni = 0; ni < 2; ++ni) {
      int br = ni * 16 + ln;
      int sw = (br & 7) << 4;
#pragma unroll
      for (int ks = 0; ks < 2; ++ks)
        kf[ni][ks] = *(const bf16x8*)(Kp + br * 128 + ((ks * 64 + g * 16) ^ sw));
    }
    bf16x8 vf[4];
#pragma unroll
    for (int di = 0; di < 4; ++di)
      vf[di] = *(const bf16x8*)(Vp + (di * 16 + ln) * 64 + ((g * 16) ^ ((ln & 3) << 4)));

    f32x4 lbf0 = {(float)ebv[0], (float)ebv[1], (float)ebv[2], (float)ebv[3]};
    f32x4 lbf1 = {(float)ebv[4], (float)ebv[5], (float)ebv[6], (float)ebv[7]};
    f32x4 s[2];
    s[0] = __builtin_amdgcn_mfma_f32_16x16x32_bf16(qf[0], kf[0][0], lbf0, 0, 0, 0);
    s[0] = __builtin_amdgcn_mfma_f32_16x16x32_bf16(qf[1], kf[0][1], s[0], 0, 0, 0);
    s[1] = __builtin_amdgcn_mfma_f32_16x16x32_bf16(qf[0], kf[1][0], lbf1, 0, 0, 0);
    s[1] = __builtin_amdgcn_mfma_f32_16x16x32_bf16(qf[1], kf[1][1], s[1], 0, 0, 0);

#pragma unroll
    for (int r = 0; r < 4; ++r) {
      float p0 = fast_exp2(s[0][r]);
      float p1 = fast_exp2(s[1][r]);
      s[0][r] = p0; s[1][r] = p1;
      l_acc[r] += p0 + p1;
    }
#pragma unroll
    for (int ni = 0; ni < 2; ++ni)
#pragma unroll
      for (int r = 0; r < 4; ++r) {
        int q = g * 4 + r;
        *(__bf16*)(Ps + q * 64 + ((ni * 32 + ln * 2) ^ (((q >> 1) & 3) << 4))) =
            (__bf16)s[ni][r];
      }
    bf16x8 pf = *(const bf16x8*)(Ps + ln * 64 + ((g * 16) ^ (((ln >> 1) & 3) << 4)));

#pragma unroll
    for (int di = 0; di < 4; ++di)
      o_acc[di] = __builtin_amdgcn_mfma_f32_16x16x32_bf16(pf, vf[di], o_acc[di], 0, 0, 0);
  };

  // prologue: period 0 into set 0; eb quad for period 0; drain; barrier
  stage(0, smem);
  f16x8 eb0 = *(const f16x8*)(ebp);
  f16x8 eb1 = *(const f16x8*)(ebp + 512);
  f16x8 eb2 = *(const f16x8*)(ebp + 1024);
  f16x8 eb3 = *(const f16x8*)(ebp + 1536);
  asm volatile("s_waitcnt vmcnt(0)" ::: "memory");
  __syncthreads();

  for (int p = 0; p < 8; ++p) {
    char* cur = smem + (p & 1) * 32768;
    char* nxt = smem + ((p + 1) & 1) * 32768;
    const int pn = (p + 1) & 7;  // wrapped prefetch period

    // [1] issue next-period staging (4 gl_lds) + eb quad for period p+1
    stage(pn, nxt);
    f16x8 ebn0 = *(const f16x8*)(ebp + (size_t)(4 * pn) * 512);
    f16x8 ebn1 = *(const f16x8*)(ebp + (size_t)(4 * pn + 1) * 512);
    f16x8 ebn2 = *(const f16x8*)(ebp + (size_t)(4 * pn + 2) * 512);
    f16x8 ebn3 = *(const f16x8*)(ebp + (size_t)(4 * pn + 3) * 512);
    __builtin_amdgcn_sched_barrier(0);

    // [2] four sub-tiles back-to-back (later frag reads overlap earlier
    //     compute -- deep within-period ILP, one barrier per 4 tiles)
    process(cur,         cur + 16384, eb0);
    process(cur + 4096,  cur + 20480, eb1);
    process(cur + 8192,  cur + 24576, eb2);
    process(cur + 12288, cur + 28672, eb3);

    // [3] drain own VMEM (issued 4 sub-tiles of compute ago); publish
    asm volatile("s_waitcnt vmcnt(0)" ::: "memory");
    __builtin_amdgcn_sched_barrier(0);
    __syncthreads();
    eb0 = ebn0; eb1 = ebn1; eb2 = ebn2; eb3 = ebn3;
  }

  // reduce l over the 16 ln-lanes, normalize, store
#pragma unroll
  for (int r = 0; r < 4; ++r) {
    float rs = l_acc[r];
#pragma unroll
    for (int off = 1; off < 16; off <<= 1)
      rs += __shfl_xor(rs, off, 64);
    float inv = 1.f / rs;
    int q = q0 + g * 4 + r;
#pragma unroll
    for (int di = 0; di < 4; ++di)
      attn[((size_t)b * 1024 + q) * 512 + h * 64 + di * 16 + ln] =
          (__bf16)(o_acc[di][r] * inv);
  }
}

extern "C" void kernel_launch(void* const* d_in, const int* in_sizes, int n_in,
                              void* d_out, int out_size, void* d_ws, size_t ws_size,
                              hipStream_t stream) {
  const float* x     = (const float*)d_in[0];
  const float* gb    = (const float*)d_in[1];
  const float* w_in  = (const float*)d_in[2];
  const float* b_in  = (const float*)d_in[3];
  const float* w_out = (const float*)d_in[4];
  const float* b_out = (const float*)d_in[5];
  const float* bstr  = (const float*)d_in[6];

  char* ws = (char*)d_ws;
  __bf16* qk    = (__bf16*)(ws);                      // 16,777,216 B
  __bf16* vT    = (__bf16*)(ws + 16777216);           //  8,388,608 B
  __bf16* xb    = (__bf16*)(ws + 25165824);           //  8,388,608 B
  __bf16* w1    = (__bf16*)(ws + 33554432);           //  1,572,864 B
  __bf16* w2    = (__bf16*)(ws + 35127296);           //    524,288 B
  _Float16* ebT = (_Float16*)(ws + 35651584);         // 16,777,216 B
  __bf16* attn_buf = xb;  // alias: x_bf16 dead after GEMM1

  prep<<<6656, 256, 0, stream>>>(gb, bstr, ebT,
                                 x, xb, (8 * 1024 * 512) / 4,
                                 w_in, w1, (1536 * 512) / 4,
                                 w_out, w2, (512 * 512) / 4);

  gemm_bt<1><<<768, 256, 0, stream>>>(xb, w1, b_in, qk, vT, 8192, 1536, 512, 12);
  attn_fused<<<512, 512, 0, stream>>>(qk, vT, ebT, attn_buf);
  gemm_bt<0><<<256, 256, 0, stream>>>(attn_buf, w2, b_out, d_out, nullptr, 8192, 512, 512, 4);
}

// Round 18
// 82.349 us; speedup vs baseline: 1.2105x; 1.0899x over previous
//
#include <hip/hip_runtime.h>

typedef __attribute__((ext_vector_type(8))) __bf16 bf16x8;
typedef __attribute__((ext_vector_type(4))) __bf16 bf16x4;
typedef __attribute__((ext_vector_type(4))) float f32x4;
typedef __attribute__((ext_vector_type(8))) _Float16 f16x8;

#define LOG2E 1.44269504088896340736f

__device__ __forceinline__ void async_load16(const void* g, void* l) {
  __builtin_amdgcn_global_load_lds(
      (const __attribute__((address_space(1))) void*)g,
      (__attribute__((address_space(3))) void*)l, 16, 0, 0);
}

__device__ __forceinline__ float fast_exp2(float x) {
#if __has_builtin(__builtin_amdgcn_exp2f)
  return __builtin_amdgcn_exp2f(x);
#else
  return __expf(x * 0.6931471805599453f);
#endif
}

// ---------------- fp32 -> bf16 convert, 3 segments ----------------
__global__ void cvt3(const float* __restrict__ a, __bf16* __restrict__ oa, int na4,
                     const float* __restrict__ b, __bf16* __restrict__ ob, int nb4,
                     const float* __restrict__ c, __bf16* __restrict__ oc, int nc4) {
  int i = blockIdx.x * blockDim.x + threadIdx.x;
  int n = na4 + nb4 + nc4;
  int stride = gridDim.x * blockDim.x;
  for (; i < n; i += stride) {
    const float4* s;
    bf16x4* d;
    int j;
    if (i < na4) { s = (const float4*)a; d = (bf16x4*)oa; j = i; }
    else if (i < na4 + nb4) { s = (const float4*)b; d = (bf16x4*)ob; j = i - na4; }
    else { s = (const float4*)c; d = (bf16x4*)oc; j = i - na4 - nb4; }
    float4 v = s[j];
    bf16x4 o;
    o[0] = (__bf16)v.x; o[1] = (__bf16)v.y; o[2] = (__bf16)v.z; o[3] = (__bf16)v.w;
    d[j] = o;
  }
}

// ---------------- gemm1 (blocks 0..767) + ebias build (768..4863) ----------
// GEMM: qkv = xb @ w1^T + b_in -> qk (Q log2-prescaled) | vT transposed.
// ebias: memory-bound table build, co-scheduled so its HBM traffic hides
// under gemm compute (no data dependency; disjoint resources).
__global__ __launch_bounds__(256) void gemm1_ebias(
    const __bf16* __restrict__ A,   // xb [8192][512]
    const __bf16* __restrict__ Bm,  // w1 [1536][512]
    const float* __restrict__ bias, // b_in [1536]
    __bf16* __restrict__ qkO,       // [8192][1024]
    __bf16* __restrict__ vT,        // [64][64][1024]
    const float* __restrict__ gbias, const float* __restrict__ bstr,
    _Float16* __restrict__ ebT) {
  __shared__ __align__(16) char smem[32768];
  const int t = threadIdx.x;

  if (blockIdx.x >= 768) {
    // ---- ebias table: ebT[(((b*64+qt)*32+kt)*64+lane)*8 + ni*4+r] ----
    const int gid = (blockIdx.x - 768) * 256 + t;
    const int lane = gid & 63;
    const int kt = (gid >> 6) & 31;
    const int qt = (gid >> 11) & 63;
    const int b = gid >> 17;
    const int g = lane >> 4, ln = lane & 15;
    const float alpha = 1.f / (1.f + __expf(-bstr[0]));
    const float bsc = 10.f * alpha * LOG2E;
    const float* base = gbias + (size_t)(b * 1024 + kt * 32 + ln) * 1024 + qt * 16 + g * 4;
    float4 va = *(const float4*)(base);              // ni=0 row
    float4 vb = *(const float4*)(base + 16 * 1024);  // ni=1 row
    float sv[8] = {va.x, va.y, va.z, va.w, vb.x, vb.y, vb.z, vb.w};
    f16x8 o;
#pragma unroll
    for (int i = 0; i < 8; ++i)
      o[i] = (_Float16)((1.f / (1.f + __expf(-sv[i])) - 0.5f) * bsc);
    *(f16x8*)(ebT + (size_t)gid * 8) = o;
    return;
  }

  // ---- GEMM part: M=8192, N=1536, K=512, 128x128 tile, XCD-chunked ----
  char* lA = smem;
  char* lB = smem + 16384;
  const int lane = t & 63;
  const int wid = t >> 6;
  const int wm = wid >> 1, wn = wid & 1;
  const int g = lane >> 4, ln = lane & 15;
  const int wg = (blockIdx.x & 7) * 96 + (blockIdx.x >> 3);  // 768/8 = 96
  const int m0 = (wg / 12) * 128;
  const int n0 = (wg % 12) * 128;

  const int srow = t >> 3;
  const int sswz = ((t & 7) * 16) ^ ((srow & 7) << 4);
  const size_t KB = 1024;  // K*2
  const char* gA = (const char*)A + (size_t)m0 * KB;
  const char* gB = (const char*)Bm + (size_t)n0 * KB;

  f32x4 acc[4][4] = {};

  for (int k0 = 0; k0 < 512; k0 += 64) {
    __syncthreads();
#pragma unroll
    for (int c = 0; c < 4; ++c) {
      int row = srow + 32 * c;
      async_load16(gA + (size_t)row * KB + k0 * 2 + sswz, lA + c * 4096 + t * 16);
      async_load16(gB + (size_t)row * KB + k0 * 2 + sswz, lB + c * 4096 + t * 16);
    }
    __syncthreads();
#pragma unroll
    for (int ks = 0; ks < 2; ++ks) {
      bf16x8 af[4], bf[4];
#pragma unroll
      for (int i = 0; i < 4; ++i) {
        int ar = wm * 64 + i * 16 + ln;
        int byo = (ks * 64 + g * 16) ^ ((ar & 7) << 4);
        af[i] = *(const bf16x8*)(lA + ar * 128 + byo);
        int br = wn * 64 + i * 16 + ln;
        bf[i] = *(const bf16x8*)(lB + br * 128 + byo);
      }
#pragma unroll
      for (int i = 0; i < 4; ++i)
#pragma unroll
        for (int j = 0; j < 4; ++j)
          acc[i][j] = __builtin_amdgcn_mfma_f32_16x16x32_bf16(af[i], bf[j], acc[i][j], 0, 0, 0);
    }
  }

#pragma unroll
  for (int j = 0; j < 4; ++j) {
    int col = n0 + wn * 64 + j * 16 + ln;
    float bv = bias[col];
    if (col < 1024) {
      float scale = (col < 512) ? (0.125f * LOG2E) : 1.0f;
#pragma unroll
      for (int i = 0; i < 4; ++i) {
        int row0 = m0 + wm * 64 + i * 16 + g * 4;
#pragma unroll
        for (int r = 0; r < 4; ++r)
          qkO[(size_t)(row0 + r) * 1024 + col] = (__bf16)((acc[i][j][r] + bv) * scale);
      }
    } else {
      int h = (col - 1024) >> 6;
      int d = (col - 1024) & 63;
#pragma unroll
      for (int i = 0; i < 4; ++i) {
        int row0 = m0 + wm * 64 + i * 16 + g * 4;
        int b = row0 >> 10;
        bf16x4 pk;
#pragma unroll
        for (int r = 0; r < 4; ++r) pk[r] = (__bf16)(acc[i][j][r] + bv);
        *(bf16x4*)(vT + (((size_t)b * 8 + h) * 64 + d) * 1024 + (row0 & 1023)) = pk;
      }
    }
  }
}

// ---------------- gemm2: out = attn @ w2^T + b_out (fp32) ----------------
__global__ __launch_bounds__(256) void gemm_bt0(
    const __bf16* __restrict__ A, const __bf16* __restrict__ Bm,
    const float* __restrict__ bias, float* __restrict__ C0,
    int M, int N, int K, int nt) {
  __shared__ __align__(16) char smem[32768];
  char* lA = smem;
  char* lB = smem + 16384;
  const int t = threadIdx.x;
  const int lane = t & 63;
  const int wid = t >> 6;
  const int wm = wid >> 1, wn = wid & 1;
  const int g = lane >> 4, ln = lane & 15;
  const int qchunk = gridDim.x >> 3;
  const int wg = (blockIdx.x & 7) * qchunk + (blockIdx.x >> 3);
  const int m0 = (wg / nt) * 128;
  const int n0 = (wg % nt) * 128;

  const int srow = t >> 3;
  const int sswz = ((t & 7) * 16) ^ ((srow & 7) << 4);
  const size_t KB = (size_t)K * 2;
  const char* gA = (const char*)A + (size_t)m0 * KB;
  const char* gB = (const char*)Bm + (size_t)n0 * KB;

  f32x4 acc[4][4] = {};

  for (int k0 = 0; k0 < K; k0 += 64) {
    __syncthreads();
#pragma unroll
    for (int c = 0; c < 4; ++c) {
      int row = srow + 32 * c;
      async_load16(gA + (size_t)row * KB + k0 * 2 + sswz, lA + c * 4096 + t * 16);
      async_load16(gB + (size_t)row * KB + k0 * 2 + sswz, lB + c * 4096 + t * 16);
    }
    __syncthreads();
#pragma unroll
    for (int ks = 0; ks < 2; ++ks) {
      bf16x8 af[4], bf[4];
#pragma unroll
      for (int i = 0; i < 4; ++i) {
        int ar = wm * 64 + i * 16 + ln;
        int byo = (ks * 64 + g * 16) ^ ((ar & 7) << 4);
        af[i] = *(const bf16x8*)(lA + ar * 128 + byo);
        int br = wn * 64 + i * 16 + ln;
        bf[i] = *(const bf16x8*)(lB + br * 128 + byo);
      }
#pragma unroll
      for (int i = 0; i < 4; ++i)
#pragma unroll
        for (int j = 0; j < 4; ++j)
          acc[i][j] = __builtin_amdgcn_mfma_f32_16x16x32_bf16(af[i], bf[j], acc[i][j], 0, 0, 0);
    }
  }

#pragma unroll
  for (int j = 0; j < 4; ++j) {
    int col = n0 + wn * 64 + j * 16 + ln;
    float bv = bias[col];
#pragma unroll
    for (int i = 0; i < 4; ++i) {
      int row0 = m0 + wm * 64 + i * 16 + g * 4;
#pragma unroll
      for (int r = 0; r < 4; ++r)
        C0[(size_t)(row0 + r) * N + col] = acc[i][j][r] + bv;
    }
  }
}

// ---------------- fused flash attention: cooperative K/V, 4 tiles/period --
// (R17-validated: 512 blocks = (b,h,qg), 8 waves, 8 periods, 72KB LDS)
__global__ __launch_bounds__(512, 4) void attn_fused(
    const __bf16* __restrict__ qk,    // [B][N][1024]: q(log2-prescaled)|k
    const __bf16* __restrict__ vT,    // [B*8][64 d][1024 k]
    const _Float16* __restrict__ ebT, // f16 bias table
    __bf16* __restrict__ attn) {      // [B][N][512]
  __shared__ __align__(16) char smem[73728];
  const int t = threadIdx.x;
  const int lane = t & 63;
  const int wid = t >> 6;               // 0..7 = q-tile within group
  const int g = lane >> 4, ln = lane & 15;
  const int wg = ((blockIdx.x & 7) << 6) + (blockIdx.x >> 3);  // XCD: b = wg>>6
  const int b = wg >> 6;
  const int rem = wg & 63;
  const int h = rem >> 3;               // head (shared by whole block)
  const int qg = rem & 7;
  const int qt = qg * 8 + wid;          // this wave's q-tile
  const int q0 = qt << 4;

  // buffer set s at smem + s*32768: [K0..K3 4K each][V0..V3 4K each]
  char* Ps = smem + 65536 + wid * 1024;  // per-wave P round-trip

  bf16x8 qf[2];
#pragma unroll
  for (int ks = 0; ks < 2; ++ks)
    qf[ks] = *(const bf16x8*)(qk + ((size_t)b * 1024 + q0 + ln) * 1024 +
                              h * 64 + ks * 32 + g * 8);

  float l_acc[4] = {0.f, 0.f, 0.f, 0.f};
  f32x4 o_acc[4] = {};

  const int krow = lane >> 3;
  const int ksrc = ((lane & 7) * 16) ^ (krow << 4);
  const int vrow = lane >> 2;
  const int vsrc = ((lane & 3) * 16) ^ ((vrow & 3) << 4);

  const char* qkb = (const char*)qk + (size_t)b * 1024 * 2048;
  const char* vTb = (const char*)vT + (size_t)(b * 8 + h) * 64 * 2048;
  const _Float16* ebp = ebT + (size_t)((b * 64 + qt) * 32) * 512 + lane * 8;

  auto stage = [&](int p, char* set) {
    if (wid < 4) {
#pragma unroll
      for (int j = 0; j < 4; ++j)
        async_load16(qkb + (size_t)((4 * p + j) * 32 + wid * 8 + krow) * 2048 +
                         1024 + h * 128 + ksrc,
                     set + j * 4096 + wid * 1024 + lane * 16);
    } else {
      int cc = wid - 4;
#pragma unroll
      for (int j = 0; j < 4; ++j)
        async_load16(vTb + (size_t)(cc * 16 + vrow) * 2048 + (size_t)(4 * p + j) * 64 + vsrc,
                     set + 16384 + j * 4096 + cc * 1024 + lane * 16);
    }
  };

  auto process = [&](const char* Kp, const char* Vp, f16x8 ebv) {
    bf16x8 kf[2][2];
#pragma unroll
    for (int ni = 0; ni < 2; ++ni) {
      int br = ni * 16 + ln;
      int sw = (br & 7) << 4;
#pragma unroll
      for (int ks = 0; ks < 2; ++ks)
        kf[ni][ks] = *(const bf16x8*)(Kp + br * 128 + ((ks * 64 + g * 16) ^ sw));
    }
    bf16x8 vf[4];
#pragma unroll
    for (int di = 0; di < 4; ++di)
      vf[di] = *(const bf16x8*)(Vp + (di * 16 + ln) * 64 + ((g * 16) ^ ((ln & 3) << 4)));

    f32x4 lbf0 = {(float)ebv[0], (float)ebv[1], (float)ebv[2], (float)ebv[3]};
    f32x4 lbf1 = {(float)ebv[4], (float)ebv[5], (float)ebv[6], (float)ebv[7]};
    f32x4 s[2];
    s[0] = __builtin_amdgcn_mfma_f32_16x16x32_bf16(qf[0], kf[0][0], lbf0, 0, 0, 0);
    s[0] = __builtin_amdgcn_mfma_f32_16x16x32_bf16(qf[1], kf[0][1], s[0], 0, 0, 0);
    s[1] = __builtin_amdgcn_mfma_f32_16x16x32_bf16(qf[0], kf[1][0], lbf1, 0, 0, 0);
    s[1] = __builtin_amdgcn_mfma_f32_16x16x32_bf16(qf[1], kf[1][1], s[1], 0, 0, 0);

#pragma unroll
    for (int r = 0; r < 4; ++r) {
      float p0 = fast_exp2(s[0][r]);
      float p1 = fast_exp2(s[1][r]);
      s[0][r] = p0; s[1][r] = p1;
      l_acc[r] += p0 + p1;
    }
#pragma unroll
    for (int ni = 0; ni < 2; ++ni)
#pragma unroll
      for (int r = 0; r < 4; ++r) {
        int q = g * 4 + r;
        *(__bf16*)(Ps + q * 64 + ((ni * 32 + ln * 2) ^ (((q >> 1) & 3) << 4))) =
            (__bf16)s[ni][r];
      }
    bf16x8 pf = *(const bf16x8*)(Ps + ln * 64 + ((g * 16) ^ (((ln >> 1) & 3) << 4)));

#pragma unroll
    for (int di = 0; di < 4; ++di)
      o_acc[di] = __builtin_amdgcn_mfma_f32_16x16x32_bf16(pf, vf[di], o_acc[di], 0, 0, 0);
  };

  stage(0, smem);
  f16x8 eb0 = *(const f16x8*)(ebp);
  f16x8 eb1 = *(const f16x8*)(ebp + 512);
  f16x8 eb2 = *(const f16x8*)(ebp + 1024);
  f16x8 eb3 = *(const f16x8*)(ebp + 1536);
  asm volatile("s_waitcnt vmcnt(0)" ::: "memory");
  __syncthreads();

  for (int p = 0; p < 8; ++p) {
    char* cur = smem + (p & 1) * 32768;
    char* nxt = smem + ((p + 1) & 1) * 32768;
    const int pn = (p + 1) & 7;

    stage(pn, nxt);
    f16x8 ebn0 = *(const f16x8*)(ebp + (size_t)(4 * pn) * 512);
    f16x8 ebn1 = *(const f16x8*)(ebp + (size_t)(4 * pn + 1) * 512);
    f16x8 ebn2 = *(const f16x8*)(ebp + (size_t)(4 * pn + 2) * 512);
    f16x8 ebn3 = *(const f16x8*)(ebp + (size_t)(4 * pn + 3) * 512);
    __builtin_amdgcn_sched_barrier(0);

    process(cur,         cur + 16384, eb0);
    process(cur + 4096,  cur + 20480, eb1);
    process(cur + 8192,  cur + 24576, eb2);
    process(cur + 12288, cur + 28672, eb3);

    asm volatile("s_waitcnt vmcnt(0)" ::: "memory");
    __builtin_amdgcn_sched_barrier(0);
    __syncthreads();
    eb0 = ebn0; eb1 = ebn1; eb2 = ebn2; eb3 = ebn3;
  }

#pragma unroll
  for (int r = 0; r < 4; ++r) {
    float rs = l_acc[r];
#pragma unroll
    for (int off = 1; off < 16; off <<= 1)
      rs += __shfl_xor(rs, off, 64);
    float inv = 1.f / rs;
    int q = q0 + g * 4 + r;
#pragma unroll
    for (int di = 0; di < 4; ++di)
      attn[((size_t)b * 1024 + q) * 512 + h * 64 + di * 16 + ln] =
          (__bf16)(o_acc[di][r] * inv);
  }
}

extern "C" void kernel_launch(void* const* d_in, const int* in_sizes, int n_in,
                              void* d_out, int out_size, void* d_ws, size_t ws_size,
                              hipStream_t stream) {
  const float* x     = (const float*)d_in[0];
  const float* gb    = (const float*)d_in[1];
  const float* w_in  = (const float*)d_in[2];
  const float* b_in  = (const float*)d_in[3];
  const float* w_out = (const float*)d_in[4];
  const float* b_out = (const float*)d_in[5];
  const float* bstr  = (const float*)d_in[6];

  char* ws = (char*)d_ws;
  __bf16* qk    = (__bf16*)(ws);                      // 16,777,216 B
  __bf16* vT    = (__bf16*)(ws + 16777216);           //  8,388,608 B
  __bf16* xb    = (__bf16*)(ws + 25165824);           //  8,388,608 B
  __bf16* w1    = (__bf16*)(ws + 33554432);           //  1,572,864 B
  __bf16* w2    = (__bf16*)(ws + 35127296);           //    524,288 B
  _Float16* ebT = (_Float16*)(ws + 35651584);         // 16,777,216 B
  __bf16* attn_buf = xb;  // alias: x_bf16 dead after GEMM1

  cvt3<<<2560, 256, 0, stream>>>(x, xb, (8 * 1024 * 512) / 4,
                                 w_in, w1, (1536 * 512) / 4,
                                 w_out, w2, (512 * 512) / 4);

  // gemm1 (768 blocks, dispatched first) + ebias table (4096 blocks) fused:
  // ebias's memory-bound traffic overlaps gemm's compute.
  gemm1_ebias<<<768 + 4096, 256, 0, stream>>>(xb, w1, b_in, qk, vT, gb, bstr, ebT);
  attn_fused<<<512, 512, 0, stream>>>(qk, vT, ebT, attn_buf);
  gemm_bt0<<<256, 256, 0, stream>>>(attn_buf, w2, b_out, (float*)d_out, 8192, 512, 512, 4);
}